// Round 14
// baseline (325.555 us; speedup 1.0000x reference)
//
#include <hip/hip_runtime.h>
#include <math.h>

#define SB 1024   // seq len
#define DM 1024   // d_model
#define BB 4      // batch
#define NH 16     // heads
#define DH 64     // head dim
#define ML 1024   // MAX_LEN

typedef __attribute__((ext_vector_type(8))) short short8;
typedef __attribute__((ext_vector_type(8))) _Float16 half8;
typedef __attribute__((ext_vector_type(4))) float f32x4;
typedef unsigned short u16;

__device__ __forceinline__ u16 f2bf(float x) {
  unsigned u = __float_as_uint(x);
  u += 0x7fffu + ((u >> 16) & 1u);
  return (u16)(u >> 16);
}
__device__ __forceinline__ float bf2f(u16 h) { return __uint_as_float((unsigned)h << 16); }

// async global->LDS, 16B per lane; lds base must be wave-uniform (HW adds lane*16)
__device__ __forceinline__ void async16(void* lds, const void* g) {
  __builtin_amdgcn_global_load_lds(
      (const __attribute__((address_space(1))) unsigned*)g,
      (__attribute__((address_space(3))) unsigned*)lds, 16, 0, 0);
}

// ======== S1: fused prep (pe | LN | optional weight packs) ========

__device__ __forceinline__ void pack16_body(int rt, int t, const float* __restrict__ src,
    _Float16* __restrict__ dH, _Float16* __restrict__ dL, float scale) {
  int r16 = t >> 4, ks = t & 15;
  const float* sp = src + (size_t)(rt * 16 + r16) * 1024 + ks * 64;
  float v[64];
  #pragma unroll
  for (int i = 0; i < 16; ++i) {
    float4 f = *(const float4*)(sp + i * 4);
    v[i*4+0] = f.x; v[i*4+1] = f.y; v[i*4+2] = f.z; v[i*4+3] = f.w;
  }
  #pragma unroll
  for (int hf = 0; hf < 2; ++hf) {
    int kt = ks * 2 + hf;
    #pragma unroll
    for (int gg = 0; gg < 4; ++gg) {
      half8 hv, lv;
      #pragma unroll
      for (int j = 0; j < 8; ++j) {
        float x = v[hf * 32 + gg * 8 + j] * scale;
        _Float16 h = (_Float16)x;
        hv[j] = h;
        lv[j] = (_Float16)(x - (float)h);
      }
      size_t off = ((size_t)(rt * 32 + kt) * 64 + r16 + gg * 16) * 8;
      *(half8*)(dH + off) = hv;
      *(half8*)(dL + off) = lv;
    }
  }
}

__device__ __forceinline__ void pe_pack_body(int rt, int t,
    _Float16* __restrict__ dH, _Float16* __restrict__ dL) {
  int r16 = t >> 4, ks = t & 15;
  int p = rt * 16 + r16;
  float v[64];
  #pragma unroll
  for (int i = 0; i < 32; ++i) {
    int c0 = ks * 64 + 2 * i;
    float div = expf((float)c0 * (-9.210340371976184f / (float)DM));
    float ang = (float)p * div;
    v[2*i]   = sinf(ang);
    v[2*i+1] = cosf(ang);
  }
  #pragma unroll
  for (int hf = 0; hf < 2; ++hf) {
    int kt = ks * 2 + hf;
    #pragma unroll
    for (int gg = 0; gg < 4; ++gg) {
      half8 hv, lv;
      #pragma unroll
      for (int j = 0; j < 8; ++j) {
        float x = v[hf * 32 + gg * 8 + j];
        _Float16 h = (_Float16)x;
        hv[j] = h;
        lv[j] = (_Float16)(x - (float)h);
      }
      size_t off = ((size_t)(rt * 32 + kt) * 64 + r16 + gg * 16) * 8;
      *(half8*)(dH + off) = hv;
      *(half8*)(dL + off) = lv;
    }
  }
}

__device__ __forceinline__ void ln_pack_body(int rt, int t, const float* __restrict__ x,
    const float* __restrict__ gamma, const float* __restrict__ beta,
    _Float16* __restrict__ dH, _Float16* __restrict__ dL) {
  int r16 = t >> 4, ks = t & 15;
  const float* sp = x + (size_t)(rt * 16 + r16) * 1024 + ks * 64;
  float v[64];
  float s1 = 0.f, s2 = 0.f;
  #pragma unroll
  for (int i = 0; i < 16; ++i) {
    float4 f = *(const float4*)(sp + i * 4);
    v[i*4+0] = f.x; v[i*4+1] = f.y; v[i*4+2] = f.z; v[i*4+3] = f.w;
    s1 += f.x + f.y + f.z + f.w;
    s2 += f.x*f.x + f.y*f.y + f.z*f.z + f.w*f.w;
  }
  #pragma unroll
  for (int off = 1; off < 16; off <<= 1) {
    s1 += __shfl_xor(s1, off, 64);
    s2 += __shfl_xor(s2, off, 64);
  }
  float mu = s1 * (1.0f / 1024.0f);
  float var = s2 * (1.0f / 1024.0f) - mu * mu;
  float rstd = rsqrtf(var + 1e-5f);
  #pragma unroll
  for (int hf = 0; hf < 2; ++hf) {
    int kt = ks * 2 + hf;
    #pragma unroll
    for (int gg = 0; gg < 4; ++gg) {
      const float* gp = gamma + ks * 64 + hf * 32 + gg * 8;
      const float* bp = beta  + ks * 64 + hf * 32 + gg * 8;
      half8 hv, lv;
      #pragma unroll
      for (int j = 0; j < 8; ++j) {
        float xn = (v[hf * 32 + gg * 8 + j] - mu) * rstd * gp[j] + bp[j];
        _Float16 h = (_Float16)xn;
        hv[j] = h;
        lv[j] = (_Float16)(xn - (float)h);
      }
      size_t off = ((size_t)(rt * 32 + kt) * 64 + r16 + gg * 16) * 8;
      *(half8*)(dH + off) = hv;
      *(half8*)(dL + off) = lv;
    }
  }
}

// launch with 320 blocks (fallback: pe+LN) or 640 (fast: + w_pos + w_tok packs)
__global__ __launch_bounds__(256) void prep_all(
    const float* __restrict__ x, const float* __restrict__ gamma,
    const float* __restrict__ beta,
    const float* __restrict__ w_pos, const float* __restrict__ w_tok,
    _Float16* __restrict__ peH, _Float16* __restrict__ peL,
    _Float16* __restrict__ xnH, _Float16* __restrict__ xnL,
    _Float16* __restrict__ wpH, _Float16* __restrict__ wpL,
    _Float16* __restrict__ wtH, _Float16* __restrict__ wtL) {
  int bid = blockIdx.x;
  int t = threadIdx.x;
  if (bid < 64)       pe_pack_body(bid, t, peH, peL);
  else if (bid < 320) ln_pack_body(bid - 64, t, x, gamma, beta, xnH, xnL);
  else if (bid < 448) pack16_body(bid - 320, t, w_pos, wpH, wpL, 32.0f);
  else                pack16_body(bid - 448, t, w_tok, wtH, wtL, 32.0f);
}

// ======== S2-fast: MERGED GEMM from prepacked planes (verified r13) ========
#define GBM 128
#define GBN 256

__global__ __launch_bounds__(256, 2) void gemm16p(
    const _Float16* __restrict__ AtH, const _Float16* __restrict__ AtL,
    const _Float16* __restrict__ ApH, const _Float16* __restrict__ ApL,
    const _Float16* __restrict__ BtH, const _Float16* __restrict__ BtL,
    const _Float16* __restrict__ BpH, const _Float16* __restrict__ BpL,
    u16* __restrict__ KtfH, u16* __restrict__ KtfL,
    u16* __restrict__ KpfH, u16* __restrict__ KpfL,
    u16* __restrict__ QH, u16* __restrict__ QL,
    u16* __restrict__ pQH, u16* __restrict__ pQL,
    u16* __restrict__ vF, float sK, float sQ, float sV) {
  __shared__ _Float16 L[32 * 512];
  int t = threadIdx.x;
  int wv = t >> 6, lane = t & 63;
  int wm = wv >> 1, wn = wv & 1;
  int r16 = lane & 15, g = lane >> 4;

  int bid = blockIdx.x;
  bool isPos = (bid >= 384);
  int idx = isPos ? bid - 384 : bid;
  int n0, m0;
  const _Float16 *AH, *AL, *BH, *BL;
  if (isPos) { n0 = (idx & 7) * 256;  m0 = (idx >> 3) * 128;
               AH = ApH; AL = ApL; BH = BpH; BL = BpL; }
  else       { n0 = (idx % 12) * 256; m0 = (idx / 12) * 128;
               AH = AtH; AL = AtL; BH = BtH; BL = BtL; }
  int mt0 = m0 >> 4, nt0 = n0 >> 4;
  bool split = isPos || (n0 < 2048);   // tok V band (n0>=2048): hh-only

  f32x4 acc[4][8];
  #pragma unroll
  for (int i = 0; i < 4; ++i)
    #pragma unroll
    for (int j = 0; j < 8; ++j) acc[i][j] = (f32x4){0.f, 0.f, 0.f, 0.f};

  for (int kt = 0; kt < 32; ++kt) {
    __syncthreads();
    #pragma unroll
    for (int rd = 0; rd < 8; ++rd) {
      int ci = rd * 4 + wv;
      bool isAlo = (ci < 16) && (ci & 1);
      if (!split && isAlo) continue;         // wave-uniform skip
      const _Float16* src;
      if (ci < 16) {
        int mt = ci >> 1, pl = ci & 1;
        const _Float16* P = pl ? AL : AH;
        src = P + ((size_t)((mt0 + mt) * 32 + kt) * 64 + lane) * 8;
      } else {
        int nt = ci - 16;
        src = BH + ((size_t)((nt0 + nt) * 32 + kt) * 64 + lane) * 8;
      }
      async16(&L[ci * 512], src);
    }
    half8 blo[8];
    if (split) {
      #pragma unroll
      for (int j = 0; j < 8; ++j) {
        int ntg = nt0 + wn * 8 + j;
        blo[j] = *(const half8*)(BL + ((size_t)(ntg * 32 + kt) * 64 + lane) * 8);
      }
    }
    __syncthreads();

    half8 ah[4], al[4];
    #pragma unroll
    for (int i = 0; i < 4; ++i)
      ah[i] = *(const half8*)&L[(((wm * 4 + i) * 2 + 0) * 512) + lane * 8];
    if (split) {
      #pragma unroll
      for (int i = 0; i < 4; ++i)
        al[i] = *(const half8*)&L[(((wm * 4 + i) * 2 + 1) * 512) + lane * 8];
    }
    #pragma unroll
    for (int j = 0; j < 8; ++j) {
      half8 bh = *(const half8*)&L[((16 + wn * 8 + j) * 512) + lane * 8];
      #pragma unroll
      for (int i = 0; i < 4; ++i) {
        acc[i][j] = __builtin_amdgcn_mfma_f32_16x16x32_f16(ah[i], bh, acc[i][j], 0, 0, 0);
        if (split) {
          acc[i][j] = __builtin_amdgcn_mfma_f32_16x16x32_f16(al[i], bh, acc[i][j], 0, 0, 0);
          acc[i][j] = __builtin_amdgcn_mfma_f32_16x16x32_f16(ah[i], blo[j], acc[i][j], 0, 0, 0);
        }
      }
    }
  }

  int band = n0 >> 10;
  u16* fKH = isPos ? KpfH : KtfH;
  u16* fKL = isPos ? KpfL : KtfL;
  u16* qHo = isPos ? pQH  : QH;
  u16* qLo = isPos ? pQL  : QL;
  if (band == 1) {
    #pragma unroll
    for (int i = 0; i < 4; ++i)
      #pragma unroll
      for (int j = 0; j < 8; ++j) {
        int lc = (n0 & 1023) + wn * 128 + j * 16 + r16;
        #pragma unroll
        for (int reg = 0; reg < 4; ++reg) {
          int row = m0 + wm * 64 + i * 16 + g * 4 + reg;
          float cv = acc[i][j][reg] * sQ;
          u16 hi = f2bf(cv);
          qHo[(size_t)row * 1024 + lc] = hi;
          qLo[(size_t)row * 1024 + lc] = f2bf(cv - bf2f(hi));
        }
      }
  } else if (band == 0) {
    #pragma unroll
    for (int i = 0; i < 4; ++i)
      #pragma unroll
      for (int j = 0; j < 8; ++j) {
        int colg = n0 + wn * 128 + j * 16 + r16;   // < 1024
        int h = colg >> 6, dc = colg & 63;
        #pragma unroll
        for (int reg = 0; reg < 4; ++reg) {
          int row = m0 + wm * 64 + i * 16 + g * 4 + reg;
          int bhK = (row >> 10) * NH + h;
          size_t a = ((size_t)((bhK * 64 + ((row & 1023) >> 4)) * 2 + (dc >> 5)) << 9)
                   + ((row & 15) + 16 * ((dc >> 3) & 3)) * 8 + (dc & 7);
          float cv = acc[i][j][reg] * sK;
          u16 hi = f2bf(cv);
          fKH[a] = hi;
          fKL[a] = f2bf(cv - bf2f(hi));
        }
      }
  } else {
    #pragma unroll
    for (int i = 0; i < 4; ++i)
      #pragma unroll
      for (int j = 0; j < 8; ++j) {
        int colg = (n0 & 1023) + wn * 128 + j * 16 + r16;
        int h = colg >> 6, dc = colg & 63;
        #pragma unroll
        for (int reg = 0; reg < 4; ++reg) {
          int row = m0 + wm * 64 + i * 16 + g * 4 + reg;
          int s = row & 1023;
          size_t a = ((size_t)((((row >> 10) * NH + h) * 32 + (s >> 5)) * 4 + (dc >> 4)) << 9)
                   + ((s >> 3) & 3) * 128 + (s & 7) + (dc & 15) * 8;
          vF[a] = f2bf(acc[i][j][reg] * sV);
        }
      }
  }
}

// ======== S2-fallback: r12 merged GEMM, B staged from fp32 originals ========
__global__ __launch_bounds__(256, 2) void gemm16m(
    const _Float16* __restrict__ AtH, const _Float16* __restrict__ AtL,
    const _Float16* __restrict__ ApH, const _Float16* __restrict__ ApL,
    const float* __restrict__ Wt, const float* __restrict__ Wp,
    u16* __restrict__ KtfH, u16* __restrict__ KtfL,
    u16* __restrict__ KpfH, u16* __restrict__ KpfL,
    u16* __restrict__ QH, u16* __restrict__ QL,
    u16* __restrict__ pQH, u16* __restrict__ pQL,
    u16* __restrict__ vF, float sK, float sQ, float sV) {
  __shared__ _Float16 L[48 * 512];
  int t = threadIdx.x;
  int wv = t >> 6, lane = t & 63;
  int wm = wv >> 1, wn = wv & 1;
  int r16 = lane & 15, g = lane >> 4;

  int bid = blockIdx.x;
  bool isPos = (bid >= 384);
  int idx = isPos ? bid - 384 : bid;
  int n0, m0;
  const _Float16 *AH, *AL;
  const float* W;
  if (isPos) { n0 = (idx & 7) * 256;  m0 = (idx >> 3) * 128; AH = ApH; AL = ApL; W = Wp; }
  else       { n0 = (idx % 12) * 256; m0 = (idx / 12) * 128; AH = AtH; AL = AtL; W = Wt; }
  int mt0 = m0 >> 4, nt0 = n0 >> 4;
  bool split = isPos || (n0 < 2048);

  f32x4 acc[4][8];
  #pragma unroll
  for (int i = 0; i < 4; ++i)
    #pragma unroll
    for (int j = 0; j < 8; ++j) acc[i][j] = (f32x4){0.f, 0.f, 0.f, 0.f};

  for (int kt = 0; kt < 32; ++kt) {
    __syncthreads();
    #pragma unroll
    for (int rd = 0; rd < 4; ++rd) {
      int ci = rd * 4 + wv;
      int mt = ci >> 1, pl = ci & 1;
      if (!split && pl) continue;
      const _Float16* src = (pl ? AL : AH)
          + ((size_t)((mt0 + mt) * 32 + kt) * 64 + lane) * 8;
      async16(&L[ci * 512], src);
    }
    #pragma unroll
    for (int tt = 0; tt < 4; ++tt) {
      int nt = wv * 4 + tt;
      const float* wsrc = W + (size_t)((nt0 + nt) * 16 + r16) * 1024 + kt * 32 + g * 8;
      float4 w0 = *(const float4*)wsrc;
      float4 w1 = *(const float4*)(wsrc + 4);
      float wvv[8] = {w0.x, w0.y, w0.z, w0.w, w1.x, w1.y, w1.z, w1.w};
      half8 hv, lv;
      #pragma unroll
      for (int j = 0; j < 8; ++j) {
        float xx = wvv[j] * 32.0f;
        _Float16 h = (_Float16)xx;
        hv[j] = h;
        lv[j] = (_Float16)(xx - (float)h);
      }
      *(half8*)&L[(16 + nt) * 512 + lane * 8] = hv;
      if (split) *(half8*)&L[(32 + nt) * 512 + lane * 8] = lv;
    }
    __syncthreads();

    half8 ah[4], al[4];
    #pragma unroll
    for (int i = 0; i < 4; ++i)
      ah[i] = *(const half8*)&L[(((wm * 4 + i) * 2 + 0) * 512) + lane * 8];
    if (split) {
      #pragma unroll
      for (int i = 0; i < 4; ++i)
        al[i] = *(const half8*)&L[(((wm * 4 + i) * 2 + 1) * 512) + lane * 8];
    }
    #pragma unroll
    for (int j = 0; j < 8; ++j) {
      half8 bh = *(const half8*)&L[((16 + wn * 8 + j) * 512) + lane * 8];
      #pragma unroll
      for (int i = 0; i < 4; ++i) {
        acc[i][j] = __builtin_amdgcn_mfma_f32_16x16x32_f16(ah[i], bh, acc[i][j], 0, 0, 0);
        if (split) {
          half8 bl = *(const half8*)&L[((32 + wn * 8 + j) * 512) + lane * 8];
          acc[i][j] = __builtin_amdgcn_mfma_f32_16x16x32_f16(al[i], bh, acc[i][j], 0, 0, 0);
          acc[i][j] = __builtin_amdgcn_mfma_f32_16x16x32_f16(ah[i], bl, acc[i][j], 0, 0, 0);
        }
      }
    }
  }

  int band = n0 >> 10;
  u16* fKH = isPos ? KpfH : KtfH;
  u16* fKL = isPos ? KpfL : KtfL;
  u16* qHo = isPos ? pQH  : QH;
  u16* qLo = isPos ? pQL  : QL;
  if (band == 1) {
    #pragma unroll
    for (int i = 0; i < 4; ++i)
      #pragma unroll
      for (int j = 0; j < 8; ++j) {
        int lc = (n0 & 1023) + wn * 128 + j * 16 + r16;
        #pragma unroll
        for (int reg = 0; reg < 4; ++reg) {
          int row = m0 + wm * 64 + i * 16 + g * 4 + reg;
          float cv = acc[i][j][reg] * sQ;
          u16 hi = f2bf(cv);
          qHo[(size_t)row * 1024 + lc] = hi;
          qLo[(size_t)row * 1024 + lc] = f2bf(cv - bf2f(hi));
        }
      }
  } else if (band == 0) {
    #pragma unroll
    for (int i = 0; i < 4; ++i)
      #pragma unroll
      for (int j = 0; j < 8; ++j) {
        int colg = n0 + wn * 128 + j * 16 + r16;
        int h = colg >> 6, dc = colg & 63;
        #pragma unroll
        for (int reg = 0; reg < 4; ++reg) {
          int row = m0 + wm * 64 + i * 16 + g * 4 + reg;
          int bhK = (row >> 10) * NH + h;
          size_t a = ((size_t)((bhK * 64 + ((row & 1023) >> 4)) * 2 + (dc >> 5)) << 9)
                   + ((row & 15) + 16 * ((dc >> 3) & 3)) * 8 + (dc & 7);
          float cv = acc[i][j][reg] * sK;
          u16 hi = f2bf(cv);
          fKH[a] = hi;
          fKL[a] = f2bf(cv - bf2f(hi));
        }
      }
  } else {
    #pragma unroll
    for (int i = 0; i < 4; ++i)
      #pragma unroll
      for (int j = 0; j < 8; ++j) {
        int colg = (n0 & 1023) + wn * 128 + j * 16 + r16;
        int h = colg >> 6, dc = colg & 63;
        #pragma unroll
        for (int reg = 0; reg < 4; ++reg) {
          int row = m0 + wm * 64 + i * 16 + g * 4 + reg;
          int s = row & 1023;
          size_t a = ((size_t)((((row >> 10) * NH + h) * 32 + (s >> 5)) * 4 + (dc >> 4)) << 9)
                   + ((s >> 3) & 3) * 128 + (s & 7) + (dc & 15) * 8;
          vF[a] = f2bf(acc[i][j][reg] * sV);
        }
      }
  }
}

// ======== S3: MFMA flash attention v10 — register diet for 3 blocks/CU ========
// r11 structure; changes: (256,3) launch bounds (170-reg budget, need ~165);
// bias read from LDS at use (no 32-reg hoist); V frags loaded AFTER the
// P-write so they reuse S's register slot (S dead there).
__global__ __launch_bounds__(256, 3) void attn_mfma10(
    const u16* __restrict__ KtfH, const u16* __restrict__ KtfL,
    const u16* __restrict__ KpfH, const u16* __restrict__ KpfL,
    const u16* __restrict__ QHg, const u16* __restrict__ QLg,
    const u16* __restrict__ pQH, const u16* __restrict__ pQL,
    const u16* __restrict__ Vf,
    const float* __restrict__ bt,
    float* __restrict__ out) {
  __shared__ u16 Pb[4][2][16 * 72];
  __shared__ float biasL[2 * ML];
  int bid = blockIdx.x;
  int qt = bid & 7;
  int bh = bid >> 3;
  int b = bh >> 4, h = bh & 15;
  int q0 = qt * 128;
  int t = threadIdx.x;
  int wv = t >> 6, lane = t & 63;
  int g = lane >> 4, r16 = lane & 15;

  #pragma unroll
  for (int k = 0; k < 8; ++k)
    biasL[t + k * 256] = bt[(size_t)(t + k * 256) * NH + h];

  short8 qhi[2][4], qlo[2][4];
  #pragma unroll
  for (int cc = 0; cc < 2; ++cc) {
    int qrow = q0 + wv * 32 + cc * 16 + r16;
    #pragma unroll
    for (int c = 0; c < 4; ++c) {
      if (c < 2) {
        size_t off = (size_t)(b * SB + qrow) * 1024 + h * DH + c * 32 + g * 8;
        qhi[cc][c] = *(const short8*)(QHg + off);
        qlo[cc][c] = *(const short8*)(QLg + off);
      } else {
        size_t off = (size_t)qrow * 1024 + h * DH + (c - 2) * 32 + g * 8;
        qhi[cc][c] = *(const short8*)(pQH + off);
        qlo[cc][c] = *(const short8*)(pQL + off);
      }
    }
  }
  __syncthreads();

  f32x4 O[2][4];
  #pragma unroll
  for (int cc = 0; cc < 2; ++cc)
    #pragma unroll
    for (int dt = 0; dt < 4; ++dt) O[cc][dt] = (f32x4){0.f, 0.f, 0.f, 0.f};
  float m_run[2][4], l_run[2][4];
  #pragma unroll
  for (int cc = 0; cc < 2; ++cc)
    #pragma unroll
    for (int reg = 0; reg < 4; ++reg) { m_run[cc][reg] = -3e38f; l_run[cc][reg] = 0.f; }

  int qb0 = q0 + wv * 32 + g * 4;
  const u16* ktH = KtfH + (size_t)(bh * 64) * 1024 + lane * 8;
  const u16* ktL = KtfL + (size_t)(bh * 64) * 1024 + lane * 8;
  const u16* kpH = KpfH + (size_t)(h * 64) * 1024 + lane * 8;
  const u16* kpL = KpfL + (size_t)(h * 64) * 1024 + lane * 8;
  const u16* vp  = Vf + (size_t)(bh * 32) * 2048 + lane * 8;
  int bb = ML + r16 - qb0;

  for (int ktr = 0; ktr < 16; ++ktr) {
    // ---- QK^T: both chains share each K B-frag (3-term split each)
    f32x4 S[2][4];
    #pragma unroll
    for (int nt = 0; nt < 4; ++nt) {
      f32x4 a0 = (f32x4){0.f, 0.f, 0.f, 0.f};
      f32x4 a1 = (f32x4){0.f, 0.f, 0.f, 0.f};
      #pragma unroll
      for (int c = 0; c < 4; ++c) {
        const u16* ph = (c < 2) ? ktH : kpH;
        const u16* pl = (c < 2) ? ktL : kpL;
        int co = (c < 2) ? c : (c - 2);
        short8 bhi = *(const short8*)(ph + nt * 1024 + co * 512);
        short8 blo = *(const short8*)(pl + nt * 1024 + co * 512);
        a0 = __builtin_amdgcn_mfma_f32_16x16x32_bf16(qhi[0][c], bhi, a0, 0, 0, 0);
        a1 = __builtin_amdgcn_mfma_f32_16x16x32_bf16(qhi[1][c], bhi, a1, 0, 0, 0);
        a0 = __builtin_amdgcn_mfma_f32_16x16x32_bf16(qlo[0][c], bhi, a0, 0, 0, 0);
        a1 = __builtin_amdgcn_mfma_f32_16x16x32_bf16(qlo[1][c], bhi, a1, 0, 0, 0);
        a0 = __builtin_amdgcn_mfma_f32_16x16x32_bf16(qhi[0][c], blo, a0, 0, 0, 0);
        a1 = __builtin_amdgcn_mfma_f32_16x16x32_bf16(qhi[1][c], blo, a1, 0, 0, 0);
      }
      S[0][nt] = a0; S[1][nt] = a1;
    }

    // ---- bias add straight from LDS (no register hoist)
    #pragma unroll
    for (int cc = 0; cc < 2; ++cc)
      #pragma unroll
      for (int nt = 0; nt < 4; ++nt)
        #pragma unroll
        for (int reg = 0; reg < 4; ++reg)
          S[cc][nt][reg] += biasL[bb - cc * 16 + nt * 16 - reg];

    // ---- online softmax
    float tm[2][4], al[2][4];
    #pragma unroll
    for (int cc = 0; cc < 2; ++cc)
      #pragma unroll
      for (int reg = 0; reg < 4; ++reg)
        tm[cc][reg] = fmaxf(fmaxf(S[cc][0][reg], S[cc][1][reg]),
                            fmaxf(S[cc][2][reg], S[cc][3][reg]));
    #pragma unroll
    for (int off = 1; off < 16; off <<= 1)
      #pragma unroll
      for (int cc = 0; cc < 2; ++cc)
        #pragma unroll
        for (int reg = 0; reg < 4; ++reg)
          tm[cc][reg] = fmaxf(tm[cc][reg], __shfl_xor(tm[cc][reg], off, 64));
    #pragma unroll
    for (int cc = 0; cc < 2; ++cc)
      #pragma unroll
      for (int reg = 0; reg < 4; ++reg) {
        float mn = fmaxf(m_run[cc][reg], tm[cc][reg]);
        al[cc][reg] = __expf(m_run[cc][reg] - mn);
        m_run[cc][reg] = mn;
      }
    float ts[2][4] = {{0.f, 0.f, 0.f, 0.f}, {0.f, 0.f, 0.f, 0.f}};
    #pragma unroll
    for (int cc = 0; cc < 2; ++cc)
      #pragma unroll
      for (int nt = 0; nt < 4; ++nt)
        #pragma unroll
        for (int reg = 0; reg < 4; ++reg) {
          float p = __expf(S[cc][nt][reg] - m_run[cc][reg]);
          S[cc][nt][reg] = p;
          ts[cc][reg] += p;
        }
    #pragma unroll
    for (int cc = 0; cc < 2; ++cc)
      #pragma unroll
      for (int reg = 0; reg < 4; ++reg)
        l_run[cc][reg] = l_run[cc][reg] * al[cc][reg] + ts[cc][reg];
    #pragma unroll
    for (int cc = 0; cc < 2; ++cc)
      #pragma unroll
      for (int dt = 0; dt < 4; ++dt)
        #pragma unroll
        for (int reg = 0; reg < 4; ++reg)
          O[cc][dt][reg] *= al[cc][reg];

    // ---- P (C-layout) -> per-wave LDS -> A-layout frags (S dies here)
    #pragma unroll
    for (int cc = 0; cc < 2; ++cc) {
      u16* pb = Pb[wv][cc];
      #pragma unroll
      for (int nt = 0; nt < 4; ++nt)
        #pragma unroll
        for (int reg = 0; reg < 4; ++reg)
          pb[(g * 4 + reg) * 72 + nt * 16 + r16] = f2bf(S[cc][nt][reg]);
    }

    // ---- V frags loaded here: reuse S's register slot
    short8 vfrag[2][4];
    #pragma unroll
    for (int kc = 0; kc < 2; ++kc)
      #pragma unroll
      for (int dt = 0; dt < 4; ++dt)
        vfrag[kc][dt] = *(const short8*)(vp + (kc * 4 + dt) * 512);

    // ---- PV: V frags shared across chains
    #pragma unroll
    for (int kc = 0; kc < 2; ++kc) {
      #pragma unroll
      for (int cc = 0; cc < 2; ++cc) {
        short8 pa = *(const short8*)&Pb[wv][cc][r16 * 72 + kc * 32 + g * 8];
        #pragma unroll
        for (int dt = 0; dt < 4; ++dt)
          O[cc][dt] = __builtin_amdgcn_mfma_f32_16x16x32_bf16(pa, vfrag[kc][dt], O[cc][dt], 0, 0, 0);
      }
    }

    ktH += 4096; ktL += 4096; kpH += 4096; kpL += 4096;
    vp += 4096; bb += 64;
  }

  #pragma unroll
  for (int off = 1; off < 16; off <<= 1)
    #pragma unroll
    for (int cc = 0; cc < 2; ++cc)
      #pragma unroll
      for (int reg = 0; reg < 4; ++reg)
        l_run[cc][reg] += __shfl_xor(l_run[cc][reg], off, 64);
  #pragma unroll
  for (int cc = 0; cc < 2; ++cc)
    #pragma unroll
    for (int reg = 0; reg < 4; ++reg) l_run[cc][reg] = 1.0f / l_run[cc][reg];
  #pragma unroll
  for (int cc = 0; cc < 2; ++cc)
    #pragma unroll
    for (int dt = 0; dt < 4; ++dt)
      #pragma unroll
      for (int reg = 0; reg < 4; ++reg)
        out[(size_t)(b * SB + qb0 + cc * 16 + reg) * DM + h * DH + dt * 16 + r16] =
            O[cc][dt][reg] * l_run[cc][reg];
}

extern "C" void kernel_launch(void* const* d_in, const int* in_sizes, int n_in,
                              void* d_out, int out_size, void* d_ws, size_t ws_size,
                              hipStream_t stream) {
  const float* x     = (const float*)d_in[0];
  const float* gamma = (const float*)d_in[1];
  const float* beta  = (const float*)d_in[2];
  const float* w_pos = (const float*)d_in[3];
  const float* w_tok = (const float*)d_in[4];
  const float* bt    = (const float*)d_in[5];
  float* out = (float*)d_out;
  float* ws  = (float*)d_ws;
  const size_t M1 = 1u << 20;
  const float IS = 11.313708498984761f;  // sqrt(2*dh)

  u16 *KtfH, *KtfL, *KpfH, *KpfL, *QH, *QL, *posQH, *posQL, *Vf;

  if (ws_size >= 22 * M1 * 4) {
    // ---- FAST path: 88 MB, prepacked weight planes, all buffers disjoint ----
    _Float16* peH = (_Float16*)(ws);
    _Float16* peL = (_Float16*)(ws + M1 / 2);
    _Float16* xnH = (_Float16*)(ws + 1 * M1);
    _Float16* xnL = (_Float16*)(ws + 3 * M1);
    _Float16* wpH = (_Float16*)(ws + 5 * M1);
    _Float16* wpL = (_Float16*)(ws + 6 * M1);
    _Float16* wtH = (_Float16*)(ws + 7 * M1);
    _Float16* wtL = (_Float16*)(ws + 8 * M1 + M1/2);
    KpfH  = (u16*)(ws + 10 * M1);
    KpfL  = (u16*)(ws + 10 * M1 + M1 / 2);
    posQH = (u16*)(ws + 11 * M1);
    posQL = (u16*)(ws + 11 * M1 + M1 / 2);
    KtfH  = (u16*)(ws + 12 * M1);
    KtfL  = (u16*)(ws + 14 * M1);
    QH    = (u16*)(ws + 16 * M1);
    QL    = (u16*)(ws + 18 * M1);
    Vf    = (u16*)(ws + 20 * M1);

    prep_all<<<640, 256, 0, stream>>>(x, gamma, beta, w_pos, w_tok,
        peH, peL, xnH, xnL, wpH, wpL, wtH, wtL);
    gemm16p<<<448, 256, 0, stream>>>(
        xnH, xnL, peH, peL, wtH, wtL, wpH, wpL,
        KtfH, KtfL, KpfH, KpfL, QH, QL, posQH, posQL, Vf,
        1.0f / 32.0f, IS / 32.0f, 1.0f / 32.0f);
  } else {
    // ---- FALLBACK: 68 MB, r12 path (B staged from fp32 originals) ----
    _Float16* peH = (_Float16*)(ws);
    _Float16* peL = (_Float16*)(ws + M1 / 2);
    _Float16* xnH = (_Float16*)(ws + 1 * M1);
    _Float16* xnL = (_Float16*)(ws + 3 * M1);
    KpfH  = (u16*)(ws + 5 * M1);
    KpfL  = (u16*)(ws + 5 * M1 + M1 / 2);
    posQH = (u16*)(ws + 6 * M1);
    posQL = (u16*)(ws + 6 * M1 + M1 / 2);
    KtfH  = (u16*)(ws + 7 * M1);
    KtfL  = (u16*)(ws + 9 * M1);
    QH    = (u16*)(ws + 11 * M1);
    QL    = (u16*)(ws + 13 * M1);
    Vf    = (u16*)(ws + 15 * M1);

    prep_all<<<320, 256, 0, stream>>>(x, gamma, beta, w_pos, w_tok,
        peH, peL, xnH, xnL, (_Float16*)nullptr, (_Float16*)nullptr,
        (_Float16*)nullptr, (_Float16*)nullptr);
    gemm16m<<<448, 256, 0, stream>>>(
        xnH, xnL, peH, peL, w_tok, w_pos,
        KtfH, KtfL, KpfH, KpfL, QH, QL, posQH, posQL, Vf,
        1.0f / 32.0f, IS / 32.0f, 1.0f / 32.0f);
  }

  attn_mfma10<<<BB * NH * (SB / 128), 256, 0, stream>>>(
      KtfH, KtfL, KpfH, KpfL, QH, QL, posQH, posQL, Vf, bt, out);
}